// Round 1
// baseline (170.676 us; speedup 1.0000x reference)
//
#include <hip/hip_runtime.h>

// PiecewiseSparseMLP: B=262144 rows, K=32 experts (10 -> 20 -> 1), distance-softmax gating.
// Round 1: fp32 baseline, one thread per row, weights via uniform (scalar) loads.

#define KX 32
#define DIN 10
#define DH 20

__global__ __launch_bounds__(256) void moe_kernel(
    const float* __restrict__ x,      // [B,10]
    const float* __restrict__ W1,     // [32,20,10]
    const float* __restrict__ b1,     // [32,20]
    const float* __restrict__ W2,     // [32,1,20]
    const float* __restrict__ b2,     // [32,1]
    const float* __restrict__ proto,  // [32,10]
    float* __restrict__ out,          // [B]
    int B)
{
    const int r = blockIdx.x * blockDim.x + threadIdx.x;
    if (r >= B) return;

    float xv[DIN];
#pragma unroll
    for (int i = 0; i < DIN; ++i) xv[i] = x[r * DIN + i];

    float num = 0.f;
    float den = 0.f;

#pragma unroll 1
    for (int k = 0; k < KX; ++k) {
        // ---- gating: dist = ||x - proto_k||, weight = exp(-dist) ----
        float d2 = 0.f;
#pragma unroll
        for (int i = 0; i < DIN; ++i) {
            const float df = xv[i] - proto[k * DIN + i];
            d2 = fmaf(df, df, d2);
        }
        const float gate = __expf(-__fsqrt_rn(d2));

        // ---- expert MLP: h = relu(W1 x + b1); pred = W2 h + b2 ----
        float pred = b2[k];
#pragma unroll
        for (int j = 0; j < DH; ++j) {
            float h = b1[k * DH + j];
#pragma unroll
            for (int i = 0; i < DIN; ++i)
                h = fmaf(W1[(k * DH + j) * DIN + i], xv[i], h);
            h = fmaxf(h, 0.f);
            pred = fmaf(W2[k * DH + j], h, pred);
        }

        num = fmaf(pred, gate, num);
        den += gate;
    }

    out[r] = num / den;
}

extern "C" void kernel_launch(void* const* d_in, const int* in_sizes, int n_in,
                              void* d_out, int out_size, void* d_ws, size_t ws_size,
                              hipStream_t stream) {
    const float* x     = (const float*)d_in[0];
    const float* W1    = (const float*)d_in[1];
    const float* b1    = (const float*)d_in[2];
    const float* W2    = (const float*)d_in[3];
    const float* b2    = (const float*)d_in[4];
    const float* proto = (const float*)d_in[5];
    float* out = (float*)d_out;

    const int B = out_size;          // D_OUT = 1
    const int block = 256;
    const int grid = (B + block - 1) / block;
    hipLaunchKernelGGL(moe_kernel, dim3(grid), dim3(block), 0, stream,
                       x, W1, b1, W2, b2, proto, out, B);
}

// Round 2
// 153.719 us; speedup vs baseline: 1.1103x; 1.1103x over previous
//
#include <hip/hip_runtime.h>

// PiecewiseSparseMLP: B=262144 rows, K=32 experts (10 -> 20 -> 1), distance-softmax gating.
// Round 2: split experts across 2 wave-groups per row to lift the grid-imposed
// 50% occupancy cap (4096 -> 8192 waves). Expert half derived via readfirstlane
// so weight indexing stays wave-uniform -> scalar (s_load) weight fetches.

#define KX 32
#define DIN 10
#define DH 20
#define ROWS_PER_BLOCK 128

__global__ __launch_bounds__(256) void moe_kernel(
    const float* __restrict__ x,      // [B,10]
    const float* __restrict__ W1,     // [32,20,10]
    const float* __restrict__ b1,     // [32,20]
    const float* __restrict__ W2,     // [32,1,20]
    const float* __restrict__ b2,     // [32,1]
    const float* __restrict__ proto,  // [32,10]
    float* __restrict__ out,          // [B]
    int B)
{
    __shared__ float s_num[ROWS_PER_BLOCK];
    __shared__ float s_den[ROWS_PER_BLOCK];

    const int tid = threadIdx.x;
    const int row_local = tid & (ROWS_PER_BLOCK - 1);
    // wave-uniform expert-half selector (waves 0,1 -> 0; waves 2,3 -> 1)
    const int half = __builtin_amdgcn_readfirstlane(tid >> 7);

    int r = blockIdx.x * ROWS_PER_BLOCK + row_local;
    if (r >= B) r = B - 1;  // B % 128 == 0 in practice; clamp is benign

    float xv[DIN];
#pragma unroll
    for (int i = 0; i < DIN; ++i) xv[i] = x[r * DIN + i];

    float num = 0.f;
    float den = 0.f;
    const int k0 = half * (KX / 2);

#pragma unroll 1
    for (int kk = 0; kk < KX / 2; ++kk) {
        const int k = k0 + kk;

        // ---- gating: dist = ||x - proto_k||, weight = exp(-dist) ----
        float d2 = 0.f;
#pragma unroll
        for (int i = 0; i < DIN; ++i) {
            const float df = xv[i] - proto[k * DIN + i];
            d2 = fmaf(df, df, d2);
        }
        const float gate = __expf(-__fsqrt_rn(d2));

        // ---- expert MLP: h = relu(W1 x + b1); pred = W2 h + b2 ----
        float pred = b2[k];
#pragma unroll
        for (int j = 0; j < DH; ++j) {
            float h = b1[k * DH + j];
#pragma unroll
            for (int i = 0; i < DIN; ++i)
                h = fmaf(W1[(k * DH + j) * DIN + i], xv[i], h);
            h = fmaxf(h, 0.f);
            pred = fmaf(W2[k * DH + j], h, pred);
        }

        num = fmaf(pred, gate, num);
        den += gate;
    }

    if (half == 1) {
        s_num[row_local] = num;
        s_den[row_local] = den;
    }
    __syncthreads();
    if (half == 0) {
        num += s_num[row_local];
        den += s_den[row_local];
        out[r] = num / den;
    }
}

extern "C" void kernel_launch(void* const* d_in, const int* in_sizes, int n_in,
                              void* d_out, int out_size, void* d_ws, size_t ws_size,
                              hipStream_t stream) {
    const float* x     = (const float*)d_in[0];
    const float* W1    = (const float*)d_in[1];
    const float* b1    = (const float*)d_in[2];
    const float* W2    = (const float*)d_in[3];
    const float* b2    = (const float*)d_in[4];
    const float* proto = (const float*)d_in[5];
    float* out = (float*)d_out;

    const int B = out_size;  // D_OUT = 1
    const int grid = (B + ROWS_PER_BLOCK - 1) / ROWS_PER_BLOCK;
    hipLaunchKernelGGL(moe_kernel, dim3(grid), dim3(256), 0, stream,
                       x, W1, b1, W2, b2, proto, out, B);
}

// Round 3
// 131.675 us; speedup vs baseline: 1.2962x; 1.1674x over previous
//
#include <hip/hip_runtime.h>

// PiecewiseSparseMLP: B=262144 rows, K=32 experts (10 -> 20 -> 1), distance-softmax gating.
// Round 3: block=512, 4-way expert split (32 waves/CU residency), all weights staged
// in LDS (broadcast ds_read_b128, no bank conflicts), layer1 via v_pk_fma_f32
// (float2 + __builtin_elementwise_fma). Hidden units processed in pairs so each
// pair's 20 W1 floats are exactly 5 aligned float4 LDS reads.

#define KX 32
#define DIN 10
#define DH 20
#define ROWS_PER_BLOCK 128
#define BLOCK 512

typedef float v2f __attribute__((ext_vector_type(2)));

__global__ __launch_bounds__(BLOCK, 8) void moe_kernel(
    const float* __restrict__ x,      // [B,10]
    const float* __restrict__ W1,     // [32,20,10] = [k][200] contiguous
    const float* __restrict__ b1,     // [32,20]
    const float* __restrict__ W2,     // [32,1,20]
    const float* __restrict__ b2,     // [32]
    const float* __restrict__ proto,  // [32,10]
    float* __restrict__ out,          // [B]
    int B)
{
    __shared__ float4 s_w1[KX * 50];   // [k][200] floats, verbatim copy of W1
    __shared__ float4 s_bw[KX * 10];   // [k][20] float2 {b1[j], w2[j]} -> 10 f4/expert
    __shared__ float4 s_pr[KX * 3];    // [k][12] floats (proto padded 10->12)
    __shared__ float  s_b2[KX];
    __shared__ v2f    s_red[3 * ROWS_PER_BLOCK];

    const int tid = threadIdx.x;

    // ---- stage weights to LDS (one-time, coalesced) ----
    {
        const float4* gW1 = (const float4*)W1;
        for (int t = tid; t < KX * 50; t += BLOCK) s_w1[t] = gW1[t];
        float2* bw = (float2*)s_bw;
        for (int t = tid; t < KX * DH; t += BLOCK) bw[t] = make_float2(b1[t], W2[t]);
        float* pr = (float*)s_pr;
        for (int t = tid; t < KX * DIN; t += BLOCK) {
            const int row = t / DIN;
            pr[row * 12 + (t - row * DIN)] = proto[t];
        }
        if (tid < KX) s_b2[tid] = b2[tid];
    }

    const int rl = tid & (ROWS_PER_BLOCK - 1);
    // wave-uniform expert-group selector (waves 2g, 2g+1 -> group g)
    const int g = __builtin_amdgcn_readfirstlane(tid >> 7);
    const int k0 = g * (KX / 4);

    int r = blockIdx.x * ROWS_PER_BLOCK + rl;
    const int rr = (r < B) ? r : (B - 1);   // B % 128 == 0 normally; clamp loads

    // x row as 5 float2 (8B-aligned: 40B * row)
    v2f xv[5];
    {
        const float2* gx = (const float2*)(x + (size_t)rr * DIN);
#pragma unroll
        for (int i = 0; i < 5; ++i) { float2 t = gx[i]; xv[i] = v2f{t.x, t.y}; }
    }

    __syncthreads();

    float num = 0.f;
    float den = 0.f;

#pragma unroll 1
    for (int kk = 0; kk < KX / 4; ++kk) {
        const int k = k0 + kk;

        // ---- gating: dist = ||x - proto_k||, gate = exp(-dist) ----
        const float4 p0 = s_pr[k * 3 + 0];
        const float4 p1 = s_pr[k * 3 + 1];
        const float4 p2 = s_pr[k * 3 + 2];
        v2f d2v = v2f{0.f, 0.f};
        {
            v2f d;
            d = xv[0] - v2f{p0.x, p0.y}; d2v = __builtin_elementwise_fma(d, d, d2v);
            d = xv[1] - v2f{p0.z, p0.w}; d2v = __builtin_elementwise_fma(d, d, d2v);
            d = xv[2] - v2f{p1.x, p1.y}; d2v = __builtin_elementwise_fma(d, d, d2v);
            d = xv[3] - v2f{p1.z, p1.w}; d2v = __builtin_elementwise_fma(d, d, d2v);
            d = xv[4] - v2f{p2.x, p2.y}; d2v = __builtin_elementwise_fma(d, d, d2v);
        }
        const float gate = __expf(-__fsqrt_rn(d2v.x + d2v.y));

        // ---- expert MLP, hidden units in pairs: 5 f4 reads + 10 pk_fma per pair ----
        float pred = s_b2[k];
        const float4* wk = &s_w1[k * 50];
        const float4* bwk = &s_bw[k * 10];
#pragma unroll
        for (int j2 = 0; j2 < DH / 2; ++j2) {
            const float4 A = wk[j2 * 5 + 0];
            const float4 Bq = wk[j2 * 5 + 1];
            const float4 C = wk[j2 * 5 + 2];
            const float4 D = wk[j2 * 5 + 3];
            const float4 E = wk[j2 * 5 + 4];

            v2f a0 = v2f{0.f, 0.f}, a1 = v2f{0.f, 0.f};
            a0 = __builtin_elementwise_fma(v2f{A.x, A.y},  xv[0], a0);
            a0 = __builtin_elementwise_fma(v2f{A.z, A.w},  xv[1], a0);
            a0 = __builtin_elementwise_fma(v2f{Bq.x, Bq.y}, xv[2], a0);
            a0 = __builtin_elementwise_fma(v2f{Bq.z, Bq.w}, xv[3], a0);
            a0 = __builtin_elementwise_fma(v2f{C.x, C.y},  xv[4], a0);
            a1 = __builtin_elementwise_fma(v2f{C.z, C.w},  xv[0], a1);
            a1 = __builtin_elementwise_fma(v2f{D.x, D.y},  xv[1], a1);
            a1 = __builtin_elementwise_fma(v2f{D.z, D.w},  xv[2], a1);
            a1 = __builtin_elementwise_fma(v2f{E.x, E.y},  xv[3], a1);
            a1 = __builtin_elementwise_fma(v2f{E.z, E.w},  xv[4], a1);

            const float4 bw = bwk[j2];   // {b1[2j2], w2[2j2], b1[2j2+1], w2[2j2+1]}
            float h0 = a0.x + a0.y + bw.x;
            h0 = fmaxf(h0, 0.f);
            pred = fmaf(bw.y, h0, pred);
            float h1 = a1.x + a1.y + bw.z;
            h1 = fmaxf(h1, 0.f);
            pred = fmaf(bw.w, h1, pred);
        }

        num = fmaf(pred, gate, num);
        den += gate;
    }

    // ---- cross-group reduction ----
    if (g) s_red[(g - 1) * ROWS_PER_BLOCK + rl] = v2f{num, den};
    __syncthreads();
    if (g == 0) {
#pragma unroll
        for (int p = 0; p < 3; ++p) {
            const v2f t = s_red[p * ROWS_PER_BLOCK + rl];
            num += t.x;
            den += t.y;
        }
        if (r < B) out[r] = num / den;
    }
}

extern "C" void kernel_launch(void* const* d_in, const int* in_sizes, int n_in,
                              void* d_out, int out_size, void* d_ws, size_t ws_size,
                              hipStream_t stream) {
    const float* x     = (const float*)d_in[0];
    const float* W1    = (const float*)d_in[1];
    const float* b1    = (const float*)d_in[2];
    const float* W2    = (const float*)d_in[3];
    const float* b2    = (const float*)d_in[4];
    const float* proto = (const float*)d_in[5];
    float* out = (float*)d_out;

    const int B = out_size;  // D_OUT = 1
    const int grid = (B + ROWS_PER_BLOCK - 1) / ROWS_PER_BLOCK;
    hipLaunchKernelGGL(moe_kernel, dim3(grid), dim3(BLOCK), 0, stream,
                       x, W1, b1, W2, b2, proto, out, B);
}